// Round 21
// baseline (86.289 us; speedup 1.0000x reference)
//
#include <hip/hip_runtime.h>

#define NSTEPS 24
#define HALFW  2048
#define INV2PI 0.15915494309189535f

typedef float float2v __attribute__((ext_vector_type(2)));

// R10 swizzle (bijective triangular XOR) — 0 conflicts measured.
#define SWZ(q) ((q) ^ (((q) >> 4) & 31) ^ (((q) >> 3) & 8))

// Phase maps for 512 threads x 8 elems (R10-verified): lane bits stay in
// q[3:0] at load (QA) and store (QD) phases => dense coalescing.
// Wave ownership: t_A[8:6]=q[8:6]; t_B/t_C/t_D[8:6]=q[11:9] =>
// QB->QC and QC->QD are WAVE-LOCAL (R20-verified, passed + faster).
#define QA(e) (((e) << 9) | t)                                  // e in 11..9
#define QB(e) ((((t) >> 6) << 9) | ((e) << 6) | ((t) & 63))     // e in 8..6
#define QC(e) ((((t) >> 3) << 6) | ((e) << 3) | ((t) & 7))      // e in 5..3
#define QD(e) (((t) << 3) | (e))                                // e in 2..0

#define SB() __builtin_amdgcn_sched_barrier(0)

// tab[d*2048 + t*4 + p] = theta/(2*pi). R10/R11-verified derivation
// (PERM = ror12; step d butterflies bit 11-(d%12); l = rotl12(q0,d%12)&0x7FF).
__global__ void build_tab_kernel(const float* __restrict__ params,
                                 float* __restrict__ tab) {
    int idx = blockIdx.x * 256 + threadIdx.x;
    if (idx >= NSTEPS * HALFW) return;
    int d  = idx >> 11;
    int j  = idx & (HALFW - 1);
    int t  = j >> 2;              // 0..511
    int p  = j & 3;               // pair index (2 bits)
    int ph = d / 3;               // phase 0..7, map = ph & 3
    int k  = 2 - (d % 3);         // butterfly bit within the 3-bit group
    int e0 = ((p >> k) << (k + 1)) | (p & ((1 << k) - 1)); // insert 0 at bit k
    int q0;
    switch (ph & 3) {
        case 0:  q0 = (e0 << 9) | t; break;
        case 1:  q0 = ((t >> 6) << 9) | (e0 << 6) | (t & 63); break;
        case 2:  q0 = ((t >> 3) << 6) | (e0 << 3) | (t & 7); break;
        default: q0 = (t << 3) | e0; break;
    }
    int dd = d % 12;
    int l = ((q0 << dd) | (q0 >> (12 - dd))) & 0xFFF;       // rotl12(q0, dd)
    l &= 0x7FF;
    float theta = params[l * NSTEPS + d];   // params (2048, 24) row-major
    tab[idx] = theta * INV2PI;
}

// 4-float theta load (one dwordx4, SROA-safe scalar unpack).
__device__ __forceinline__ void ldth4(float (&dst)[4], const float* __restrict__ p) {
    float4 q = *(const float4*)p;
    dst[0] = q.x; dst[1] = q.y; dst[2] = q.z; dst[3] = q.w;
}

// Packed butterfly on bit KK, SINGLE pipeline (2 rows). R21: trades the
// R11 sincos amortization for a 3rd block/CU — R15 proved sincos ISSUE is
// free (latency-bound kernel); the extra residency is what covers latency.
template<int KK>
__device__ __forceinline__ void bfly1(float2v (&ra)[8], const float (&th)[4]) {
    #pragma unroll
    for (int p = 0; p < 4; ++p) {
        const int e0 = ((p >> KK) << (KK + 1)) | (p & ((1 << KK) - 1));
        const int e1 = e0 | (1 << KK);
        const float c = __builtin_amdgcn_cosf(th[p]);
        const float s = __builtin_amdgcn_sinf(th[p]);
        const float2v cv = {c, c};
        const float2v sv = {s, s};
        const float2v a0 = ra[e0], a1 = ra[e1];
        ra[e0] = __builtin_elementwise_fma(cv, a0, sv * a1);
        ra[e1] = __builtin_elementwise_fma(cv, a1, -(sv * a0));
    }
}

// 3 butterfly steps (one phase); TRIPLE theta buffer, distance-3 prefetch
// pinned after each last use (R19: -4.6% vs distance-2; R13: distance-1
// regresses; R16: unpinned regresses). Static rotation. No setprio (R17).
template<int BASE>
__device__ __forceinline__ void group3(float2v (&ra)[8],
        float (&t0)[4], float (&t1)[4], float (&t2)[4],
        const float* __restrict__ tb) {
    bfly1<2>(ra, t0);
    if constexpr (BASE + 3 < NSTEPS) { ldth4(t0, tb + (BASE + 3) * 2048); SB(); }
    bfly1<1>(ra, t1);
    if constexpr (BASE + 4 < NSTEPS) { ldth4(t1, tb + (BASE + 4) * 2048); SB(); }
    bfly1<0>(ra, t2);
    if constexpr (BASE + 5 < NSTEPS) { ldth4(t2, tb + (BASE + 5) * 2048); SB(); }
}

// Cross-wave transpose: write, BARRIER, read. R9 bijection covers
// read->next-write (same thread, in-order DS pipe).
#define TRANS_X(QS, QDm) do {                                                 \
    _Pragma("unroll")                                                         \
    for (int e = 0; e < 8; ++e)                                               \
        lds[SWZ(QS(e))] = rp[e];                                              \
    __syncthreads();                                                          \
    _Pragma("unroll")                                                         \
    for (int e = 0; e < 8; ++e)                                               \
        rp[e] = lds[SWZ(QDm(e))];                                             \
} while (0)

// WAVE-LOCAL transpose (QB->QC, QC->QD): NO block barrier (R20-verified:
// passed correctness AND faster). Per-wave DS pipe is in-order; SB pins
// compiler ordering; cross-thread WAR pairs are same-thread (R9 bijection).
#define TRANS_L(QS, QDm) do {                                                 \
    _Pragma("unroll")                                                         \
    for (int e = 0; e < 8; ++e)                                               \
        lds[SWZ(QS(e))] = rp[e];                                              \
    SB();                                                                     \
    _Pragma("unroll")                                                         \
    for (int e = 0; e < 8; ++e)                                               \
        rp[e] = lds[SWZ(QDm(e))];                                             \
} while (0)

// (512,2): natural allocation (R12: never squeeze below essential).
// rows=2 state: rp 16 + tq 12 + addr ~10 = ~38-40 VGPR (R10 measured 36
// for this shape + theta dbuf) -> floor(256/40) = 6 waves/SIMD ->
// 3 blocks/CU with 32 KiB LDS (96 KiB/CU). +50% residency vs R20 at the
// cost of 2x sincos/theta per row — the occupancy-vs-amortization A/B.
__global__ __launch_bounds__(512, 2)
void bfly_kernel(const float* __restrict__ X,
                 const float* __restrict__ tab,
                 float* __restrict__ Y) {
    __shared__ float2v lds[4096];      // 32 KiB, single pipeline
    const int t = threadIdx.x;
    const size_t row0 = (size_t)blockIdx.x * 2;

    const float* tb = tab + t * 4;
    float tq0[4], tq1[4], tq2[4];
    ldth4(tq0, tb + 0 * 2048);
    ldth4(tq1, tb + 1 * 2048);
    ldth4(tq2, tb + 2 * 2048);
    SB();

    float2v rp[8];                     // rows row0, row0+1
    {
        const float* x0 = X + row0 * 4096;
        const float* x1 = x0 + 4096;
        #pragma unroll
        for (int e = 0; e < 8; ++e) {
            const int a = QA(e);   // consecutive lanes, consecutive addresses
            rp[e].x = x0[a];
            rp[e].y = x1[a];
        }
    }

    group3<0 >(rp, tq0, tq1, tq2, tb);   TRANS_X(QA, QB);   // T1 cross
    group3<3 >(rp, tq0, tq1, tq2, tb);   TRANS_L(QB, QC);   // T2 wave-local
    group3<6 >(rp, tq0, tq1, tq2, tb);   TRANS_L(QC, QD);   // T3 wave-local
    group3<9 >(rp, tq0, tq1, tq2, tb);   TRANS_X(QD, QA);   // T4 cross
    group3<12>(rp, tq0, tq1, tq2, tb);   TRANS_X(QA, QB);   // T5 cross
    group3<15>(rp, tq0, tq1, tq2, tb);   TRANS_L(QB, QC);   // T6 wave-local
    group3<18>(rp, tq0, tq1, tq2, tb);   TRANS_L(QC, QD);   // T7 wave-local
    group3<21>(rp, tq0, tq1, tq2, tb);                      // steps 21..23

    // QD layout: thread t holds 8 consecutive columns at t*8, 2 rows.
    {
        float* y0 = Y + row0 * 4096 + (t << 3);
        float* y1 = y0 + 4096;
        float4 v;
        v.x = rp[0].x; v.y = rp[1].x; v.z = rp[2].x; v.w = rp[3].x;
        *(float4*)&y0[0] = v;
        v.x = rp[4].x; v.y = rp[5].x; v.z = rp[6].x; v.w = rp[7].x;
        *(float4*)&y0[4] = v;
        v.x = rp[0].y; v.y = rp[1].y; v.z = rp[2].y; v.w = rp[3].y;
        *(float4*)&y1[0] = v;
        v.x = rp[4].y; v.y = rp[5].y; v.z = rp[6].y; v.w = rp[7].y;
        *(float4*)&y1[4] = v;
    }
}

extern "C" void kernel_launch(void* const* d_in, const int* in_sizes, int n_in,
                              void* d_out, int out_size, void* d_ws, size_t ws_size,
                              hipStream_t stream) {
    const float* X      = (const float*)d_in[0];
    const float* params = (const float*)d_in[1];
    float* out = (float*)d_out;
    float* tab = (float*)d_ws;   // 24*2048*4 = 196,608 bytes (theta only)

    hipLaunchKernelGGL(build_tab_kernel,
                       dim3((NSTEPS * HALFW + 255) / 256), dim3(256), 0, stream,
                       params, tab);
    hipLaunchKernelGGL(bfly_kernel,
                       dim3(8192 / 2), dim3(512), 0, stream,
                       X, tab, out);
}

// Round 22
// 77.715 us; speedup vs baseline: 1.1103x; 1.1103x over previous
//
#include <hip/hip_runtime.h>

#define NSTEPS 24
#define HALFW  2048
#define INV2PI 0.15915494309189535f

typedef float float2v __attribute__((ext_vector_type(2)));

// R10 swizzle (bijective triangular XOR) — 0 conflicts measured with the
// R14 split-buffer TRANS.
#define SWZ(q) ((q) ^ (((q) >> 4) & 31) ^ (((q) >> 3) & 8))

// Phase maps for 512 threads x 8 elems (R10-verified): lane bits stay in
// q[3:0] at load (QA) and store (QD) phases => dense coalescing.
// Wave ownership of column q: t_A[8:6]=q[8:6]; t_B/t_C/t_D[8:6]=q[11:9].
// => QB->QC and QC->QD preserve the wave id: WAVE-LOCAL transposes.
#define QA(e) (((e) << 9) | t)                                  // e in 11..9
#define QB(e) ((((t) >> 6) << 9) | ((e) << 6) | ((t) & 63))     // e in 8..6
#define QC(e) ((((t) >> 3) << 6) | ((e) << 3) | ((t) & 7))      // e in 5..3
#define QD(e) (((t) << 3) | (e))                                // e in 2..0

#define SB() __builtin_amdgcn_sched_barrier(0)

// tab[d*2048 + t*4 + p] = theta/(2*pi). R10/R11-verified derivation
// (PERM = ror12; step d butterflies bit 11-(d%12); l = rotl12(q0,d%12)&0x7FF).
__global__ void build_tab_kernel(const float* __restrict__ params,
                                 float* __restrict__ tab) {
    int idx = blockIdx.x * 256 + threadIdx.x;
    if (idx >= NSTEPS * HALFW) return;
    int d  = idx >> 11;
    int j  = idx & (HALFW - 1);
    int t  = j >> 2;              // 0..511
    int p  = j & 3;               // pair index (2 bits)
    int ph = d / 3;               // phase 0..7, map = ph & 3
    int k  = 2 - (d % 3);         // butterfly bit within the 3-bit group
    int e0 = ((p >> k) << (k + 1)) | (p & ((1 << k) - 1)); // insert 0 at bit k
    int q0;
    switch (ph & 3) {
        case 0:  q0 = (e0 << 9) | t; break;
        case 1:  q0 = ((t >> 6) << 9) | (e0 << 6) | (t & 63); break;
        case 2:  q0 = ((t >> 3) << 6) | (e0 << 3) | (t & 7); break;
        default: q0 = (t << 3) | e0; break;
    }
    int dd = d % 12;
    int l = ((q0 << dd) | (q0 >> (12 - dd))) & 0xFFF;       // rotl12(q0, dd)
    l &= 0x7FF;
    float theta = params[l * NSTEPS + d];   // params (2048, 24) row-major
    tab[idx] = theta * INV2PI;
}

// 4-float theta load (one dwordx4, SROA-safe scalar unpack).
__device__ __forceinline__ void ldth4(float (&dst)[4], const float* __restrict__ p) {
    float4 q = *(const float4*)p;
    dst[0] = q.x; dst[1] = q.y; dst[2] = q.z; dst[3] = q.w;
}

// Packed butterfly on bit KK applied to BOTH pipelines (4 rows) with ONE
// sincos evaluation (column-determined, row-independent). 8 independent
// pk-FMA chains per p. R21 closed the A/B: this 4-row amortization at
// 2 blocks/CU BEATS 3-blocks/CU without it (78.7 vs 86.3) — sincos/theta
// amortization + conflict-free split buffers outweigh +50% residency.
template<int KK>
__device__ __forceinline__ void bfly2(float2v (&ra)[8], float2v (&rb)[8],
                                      const float (&th)[4]) {
    #pragma unroll
    for (int p = 0; p < 4; ++p) {
        const int e0 = ((p >> KK) << (KK + 1)) | (p & ((1 << KK) - 1));
        const int e1 = e0 | (1 << KK);
        const float c = __builtin_amdgcn_cosf(th[p]);
        const float s = __builtin_amdgcn_sinf(th[p]);
        const float2v cv = {c, c};
        const float2v sv = {s, s};
        const float2v a0 = ra[e0], a1 = ra[e1];
        ra[e0] = __builtin_elementwise_fma(cv, a0, sv * a1);
        ra[e1] = __builtin_elementwise_fma(cv, a1, -(sv * a0));
        const float2v b0 = rb[e0], b1 = rb[e1];
        rb[e0] = __builtin_elementwise_fma(cv, b0, sv * b1);
        rb[e1] = __builtin_elementwise_fma(cv, b1, -(sv * b0));
    }
}

// 3 butterfly steps (one phase); TRIPLE theta buffer, distance-3 prefetch
// pinned after each last use (R19: -4.6% rocprof vs distance-2; R13:
// distance-1 regresses; R16: unpinned regresses). Static rotation, no
// parity branch. No setprio (R17: -3.8us at 2 blocks/CU lockstep).
template<int BASE>
__device__ __forceinline__ void group3(float2v (&ra)[8], float2v (&rb)[8],
        float (&t0)[4], float (&t1)[4], float (&t2)[4],
        const float* __restrict__ tb) {
    bfly2<2>(ra, rb, t0);
    if constexpr (BASE + 3 < NSTEPS) { ldth4(t0, tb + (BASE + 3) * 2048); SB(); }
    bfly2<1>(ra, rb, t1);
    if constexpr (BASE + 4 < NSTEPS) { ldth4(t1, tb + (BASE + 4) * 2048); SB(); }
    bfly2<0>(ra, rb, t2);
    if constexpr (BASE + 5 < NSTEPS) { ldth4(t2, tb + (BASE + 5) * 2048); SB(); }
}

// Cross-wave transpose (QA->QB, QD->QA): write, BARRIER, read.
// R9 bijection covers read->next-write (same thread, in-order DS pipe).
#define TRANS_X(QS, QDm) do {                                                 \
    _Pragma("unroll")                                                         \
    for (int e = 0; e < 8; ++e) {                                             \
        const int a = SWZ(QS(e));                                             \
        ldsA[a] = rpA[e];                                                     \
        ldsB[a] = rpB[e];                                                     \
    }                                                                         \
    __syncthreads();                                                          \
    _Pragma("unroll")                                                         \
    for (int e = 0; e < 8; ++e) {                                             \
        const int a = SWZ(QDm(e));                                            \
        rpA[e] = ldsA[a];                                                     \
        rpB[e] = ldsB[a];                                                     \
    }                                                                         \
} while (0)

// WAVE-LOCAL transpose (QB->QC, QC->QD: owner wave id t[8:6] = q[11:9] on
// both sides): NO block barrier (R20-verified: passed correctness AND
// faster). Per-wave DS pipe is in-order; SB pins compiler ordering;
// cross-thread WAR pairs are same-thread (R9 bijection).
#define TRANS_L(QS, QDm) do {                                                 \
    _Pragma("unroll")                                                         \
    for (int e = 0; e < 8; ++e) {                                             \
        const int a = SWZ(QS(e));                                             \
        ldsA[a] = rpA[e];                                                     \
        ldsB[a] = rpB[e];                                                     \
    }                                                                         \
    SB();                                                                     \
    _Pragma("unroll")                                                         \
    for (int e = 0; e < 8; ++e) {                                             \
        const int a = SWZ(QDm(e));                                            \
        rpA[e] = ldsA[a];                                                     \
        rpB[e] = ldsB[a];                                                     \
    }                                                                         \
} while (0)

// RECORD CONFIGURATION (R20: 78.7 us, from R0 baseline 105.8 = -26%).
// (512,4) caps VGPR at 64; measured 52 -> 2 blocks/CU (VGPR & LDS capped
// simultaneously). Session ledger: issue-count halvings all null
// (latency-structure-bound); occupancy probed both directions (R10/R21);
// barriers 21->3; prefetch distance bracketed at 3; setprio negative;
// allocator squeezes spill; coalescing maps non-negotiable.
__global__ __launch_bounds__(512, 4)
void bfly_kernel(const float* __restrict__ X,
                 const float* __restrict__ tab,
                 float* __restrict__ Y) {
    __shared__ float2v ldsA[4096];     // 32 KiB, pipeline A (rows 0,1)
    __shared__ float2v ldsB[4096];     // 32 KiB, pipeline B (rows 2,3)
    const int t = threadIdx.x;
    const size_t row0 = (size_t)blockIdx.x * 4;

    const float* tb = tab + t * 4;
    float tq0[4], tq1[4], tq2[4];
    ldth4(tq0, tb + 0 * 2048);
    ldth4(tq1, tb + 1 * 2048);
    ldth4(tq2, tb + 2 * 2048);
    SB();

    float2v rpA[8], rpB[8];            // A: rows 0,1  B: rows 2,3
    {
        const float* x0 = X + row0 * 4096;
        const float* x1 = x0 + 4096;
        const float* x2 = x0 + 8192;
        const float* x3 = x0 + 12288;
        #pragma unroll
        for (int e = 0; e < 8; ++e) {
            const int a = QA(e);   // consecutive lanes, consecutive addresses
            rpA[e].x = x0[a];
            rpA[e].y = x1[a];
            rpB[e].x = x2[a];
            rpB[e].y = x3[a];
        }
    }

    group3<0 >(rpA, rpB, tq0, tq1, tq2, tb);   TRANS_X(QA, QB);   // T1 cross
    group3<3 >(rpA, rpB, tq0, tq1, tq2, tb);   TRANS_L(QB, QC);   // T2 wave-local
    group3<6 >(rpA, rpB, tq0, tq1, tq2, tb);   TRANS_L(QC, QD);   // T3 wave-local
    group3<9 >(rpA, rpB, tq0, tq1, tq2, tb);   TRANS_X(QD, QA);   // T4 cross
    group3<12>(rpA, rpB, tq0, tq1, tq2, tb);   TRANS_X(QA, QB);   // T5 cross
    group3<15>(rpA, rpB, tq0, tq1, tq2, tb);   TRANS_L(QB, QC);   // T6 wave-local
    group3<18>(rpA, rpB, tq0, tq1, tq2, tb);   TRANS_L(QC, QD);   // T7 wave-local
    group3<21>(rpA, rpB, tq0, tq1, tq2, tb);                      // steps 21..23

    // QD layout: thread t holds 8 consecutive columns at t*8, 4 rows.
    {
        float* y0 = Y + row0 * 4096 + (t << 3);
        float* y1 = y0 + 4096;
        float* y2 = y0 + 8192;
        float* y3 = y0 + 12288;
        float4 v;
        v.x = rpA[0].x; v.y = rpA[1].x; v.z = rpA[2].x; v.w = rpA[3].x;
        *(float4*)&y0[0] = v;
        v.x = rpA[4].x; v.y = rpA[5].x; v.z = rpA[6].x; v.w = rpA[7].x;
        *(float4*)&y0[4] = v;
        v.x = rpA[0].y; v.y = rpA[1].y; v.z = rpA[2].y; v.w = rpA[3].y;
        *(float4*)&y1[0] = v;
        v.x = rpA[4].y; v.y = rpA[5].y; v.z = rpA[6].y; v.w = rpA[7].y;
        *(float4*)&y1[4] = v;
        v.x = rpB[0].x; v.y = rpB[1].x; v.z = rpB[2].x; v.w = rpB[3].x;
        *(float4*)&y2[0] = v;
        v.x = rpB[4].x; v.y = rpB[5].x; v.z = rpB[6].x; v.w = rpB[7].x;
        *(float4*)&y2[4] = v;
        v.x = rpB[0].y; v.y = rpB[1].y; v.z = rpB[2].y; v.w = rpB[3].y;
        *(float4*)&y3[0] = v;
        v.x = rpB[4].y; v.y = rpB[5].y; v.z = rpB[6].y; v.w = rpB[7].y;
        *(float4*)&y3[4] = v;
    }
}

extern "C" void kernel_launch(void* const* d_in, const int* in_sizes, int n_in,
                              void* d_out, int out_size, void* d_ws, size_t ws_size,
                              hipStream_t stream) {
    const float* X      = (const float*)d_in[0];
    const float* params = (const float*)d_in[1];
    float* out = (float*)d_out;
    float* tab = (float*)d_ws;   // 24*2048*4 = 196,608 bytes (theta only)

    hipLaunchKernelGGL(build_tab_kernel,
                       dim3((NSTEPS * HALFW + 255) / 256), dim3(256), 0, stream,
                       params, tab);
    hipLaunchKernelGGL(bfly_kernel,
                       dim3(8192 / 4), dim3(512), 0, stream,
                       X, tab, out);
}